// Round 1
// 356.651 us; speedup vs baseline: 1.1072x; 1.1072x over previous
//
#include <hip/hip_runtime.h>
#include <stdint.h>

#define TSTEPS 512
#define BATCH  4096
// R16: 16 rows/block (FULL 16-row MFMA A-tile, was half-zero), grid 256x512,
// launch_bounds(512,2) (1 block/CU, full reg budget, no AGPR churn).
// Theory: halves MFMA count and LDS b128 reads per CU-step; EW (VALU,
// conserved) doubled per wave as two f32x2 pipelines over acc rows 0..3.
// Prior structure (R15): 512 blocks x 8 rows, 2 blocks/CU, 373 us steady.
// Failed variants: R9 swizzle-store, R11 x-in-LDS, R12 4-deep MFMA chains,
// R13 shared-rcp, R14 occupancy push (spill).

typedef __attribute__((ext_vector_type(8))) short bf16x8;
typedef __attribute__((ext_vector_type(4))) float f32x4;
typedef __attribute__((ext_vector_type(2))) float f32x2;

#define SRZ (-1.4426950408889634f)   /* -log2(e): r,z gates */
#define SN  ( 2.8853900817779268f)   /* 2*log2(e): n gate   */

__device__ __forceinline__ short f2bf(float f) {
    uint32_t u = __float_as_uint(f);
    uint32_t r = (u + 0x7fffu + ((u >> 16) & 1u)) >> 16;
    return (short)r;
}
__device__ __forceinline__ float fast_rcp(float x) { return __builtin_amdgcn_rcpf(x); }
#if __has_builtin(__builtin_amdgcn_exp2f)
__device__ __forceinline__ float exp2_fast(float x) { return __builtin_amdgcn_exp2f(x); }
#else
__device__ __forceinline__ float exp2_fast(float x) { return __expf(x * 0.6931471805599453f); }
#endif

__device__ __forceinline__ f32x2 fma2(f32x2 a, f32x2 b, f32x2 c) {
    return __builtin_elementwise_fma(a, b, c);
}
__device__ __forceinline__ f32x2 splat2(float s) { return (f32x2){s, s}; }
// sigmoid of pre-scaled arg: rcp(1 + exp2(y)), over 2 rows
__device__ __forceinline__ f32x2 sig2(f32x2 y) {
    f32x2 a = {exp2_fast(y[0]), exp2_fast(y[1])};
    a = a + splat2(1.0f);                     // v_pk_add_f32
    return (f32x2){fast_rcp(a[0]), fast_rcp(a[1])};
}
// tanh of pre-scaled arg: 1 - 2*sig2(y)
__device__ __forceinline__ f32x2 tanh2(f32x2 y) {
    return fma2(splat2(-2.0f), sig2(y), splat2(1.0f));
}

__global__ __launch_bounds__(512, 2) void gru_fused(
    const float* __restrict__ x,     // [T,B,2]
    const float* __restrict__ Wih0,  // [192,2]
    const float* __restrict__ Whh0,  // [192,64]
    const float* __restrict__ bih0,  // [192]
    const float* __restrict__ bhh0,  // [192]
    const float* __restrict__ Wih1,  // [192,64]
    const float* __restrict__ Whh1,  // [192,64]
    const float* __restrict__ bih1,  // [192]
    const float* __restrict__ bhh1,  // [192]
    const float* __restrict__ Wp,    // [128]
    const float* __restrict__ bp,    // [1]
    float* __restrict__ out)         // [B]
{
    const int tid  = threadIdx.x;
    const int wv   = tid >> 6;      // wave 0..7
    const int isL0 = (wv < 4);
    const int w4   = wv & 3;
    const int l    = tid & 63;
    const int lm   = l & 15;        // A row m / n-col within tile
    const int lq   = l >> 4;        // quad
    const int b0   = blockIdx.x * 16;
    const int j    = w4 * 16 + lm;  // hidden index this lane owns

    // All 16 MFMA A rows are live batch rows: row m = batch b0+m.
    // EW lane (lm,lq) owns acc rows lq*4+0..3 at hidden j.
    __shared__ short h0A[2][16 * 72];
    __shared__ short h1A[2][16 * 72];
    __shared__ float Pf[16][64];

    for (int idx = tid; idx < 2 * 16 * 72; idx += 512) {
        ((short*)h0A)[idx] = 0;
        ((short*)h1A)[idx] = 0;
    }
    __syncthreads();

    const int aoff = lm * 72 + lq * 8;  // shorts; +32 for K-half 1
    const int r0   = lq * 4;            // first of this lane's 4 rows

    if (isL0) {
        // ================= layer-0 waves =================
        bf16x8 w0[3][2];   // Whh0, gate-prescaled, single bf16
#pragma unroll
        for (int g = 0; g < 3; ++g) {
            const int row = g * 64 + j;
            const float sc = (g == 2) ? SN : SRZ;
#pragma unroll
            for (int q = 0; q < 2; ++q) {
                const float* p = Whh0 + row * 64 + q * 32 + lq * 8;
                bf16x8 vh;
#pragma unroll
                for (int i = 0; i < 8; ++i) vh[i] = f2bf(p[i] * sc);
                w0[g][q] = vh;
            }
        }
        const f32x2 wr0 = splat2(SRZ * Wih0[j * 2 + 0]), wr1 = splat2(SRZ * Wih0[j * 2 + 1]);
        const f32x2 wz0 = splat2(SRZ * Wih0[(64 + j) * 2 + 0]), wz1 = splat2(SRZ * Wih0[(64 + j) * 2 + 1]);
        const f32x2 wn0 = splat2(SN * Wih0[(128 + j) * 2 + 0]), wn1 = splat2(SN * Wih0[(128 + j) * 2 + 1]);
        const float cb[3] = { SRZ * (bih0[j] + bhh0[j]),
                              SRZ * (bih0[64 + j] + bhh0[64 + j]),
                              SN  * bhh0[128 + j] };
        const f32x2 bn = splat2(SN * bih0[128 + j]);

        f32x2 h01 = {0.f, 0.f}, h23 = {0.f, 0.f};
        const float* xp = x + (size_t)(b0 + r0) * 2;    // 4 rows x 2 floats
        f32x4 xa = *(const f32x4*)xp;
        f32x4 xb = *(const f32x4*)(xp + 4);
        f32x4 xan = xa, xbn = xb;

        for (int t = 0; t <= TSTEPS; ++t) {
            const int pr = t & 1, pw = pr ^ 1;
            bf16x8 a00 = *(const bf16x8*)&h0A[pr][aoff];
            bf16x8 a01 = *(const bf16x8*)&h0A[pr][aoff + 32];

            if (t + 1 < TSTEPS) {
                xp += (size_t)BATCH * 2;
                xan = *(const f32x4*)xp;
                xbn = *(const f32x4*)(xp + 4);
            }

            f32x4 hg0[3];
#pragma unroll
            for (int g = 0; g < 3; ++g) {
                const f32x4 ci = {cb[g], cb[g], cb[g], cb[g]};
                f32x4 c;
                c = __builtin_amdgcn_mfma_f32_16x16x32_bf16(a00, w0[g][0], ci, 0, 0, 0);
                hg0[g] = __builtin_amdgcn_mfma_f32_16x16x32_bf16(a01, w0[g][1], c, 0, 0, 0);
            }

            if (t < TSTEPS) {
                {   // rows r0+0, r0+1 (acc regs 0,1 — adjacent -> free f32x2)
                    const f32x2 x0v = {xa[0], xa[2]}, x1v = {xa[1], xa[3]};
                    const f32x2 hgr = {hg0[0][0], hg0[0][1]};
                    const f32x2 hgz = {hg0[1][0], hg0[1][1]};
                    const f32x2 hgn = {hg0[2][0], hg0[2][1]};
                    const f32x2 rv = sig2(fma2(wr0, x0v, fma2(wr1, x1v, hgr)));
                    const f32x2 zv = sig2(fma2(wz0, x0v, fma2(wz1, x1v, hgz)));
                    const f32x2 nv = tanh2(fma2(rv, hgn, fma2(wn0, x0v, fma2(wn1, x1v, bn))));
                    const f32x2 hv = fma2(zv, h01 - nv, nv);
                    h01 = hv;
                    h0A[pw][(r0 + 0) * 72 + j] = f2bf(hv[0]);
                    h0A[pw][(r0 + 1) * 72 + j] = f2bf(hv[1]);
                }
                {   // rows r0+2, r0+3 (acc regs 2,3)
                    const f32x2 x0v = {xb[0], xb[2]}, x1v = {xb[1], xb[3]};
                    const f32x2 hgr = {hg0[0][2], hg0[0][3]};
                    const f32x2 hgz = {hg0[1][2], hg0[1][3]};
                    const f32x2 hgn = {hg0[2][2], hg0[2][3]};
                    const f32x2 rv = sig2(fma2(wr0, x0v, fma2(wr1, x1v, hgr)));
                    const f32x2 zv = sig2(fma2(wz0, x0v, fma2(wz1, x1v, hgz)));
                    const f32x2 nv = tanh2(fma2(rv, hgn, fma2(wn0, x0v, fma2(wn1, x1v, bn))));
                    const f32x2 hv = fma2(zv, h23 - nv, nv);
                    h23 = hv;
                    h0A[pw][(r0 + 2) * 72 + j] = f2bf(hv[0]);
                    h0A[pw][(r0 + 3) * 72 + j] = f2bf(hv[1]);
                }
            }
            xa = xan; xb = xbn;
            __syncthreads();   // barrier 1..513
        }

        const float wp0 = Wp[j];
        Pf[r0 + 0][j] = wp0 * h01[0];
        Pf[r0 + 1][j] = wp0 * h01[1];
        Pf[r0 + 2][j] = wp0 * h23[0];
        Pf[r0 + 3][j] = wp0 * h23[1];
        __syncthreads();       // barrier 514
        __syncthreads();       // barrier 515
    } else {
        // ================= layer-1 waves =================
        bf16x8 w1[3][2], w2[3][2];   // Wih1, Whh1, gate-prescaled, single bf16
#pragma unroll
        for (int g = 0; g < 3; ++g) {
            const int row = g * 64 + j;
            const float sc = (g == 2) ? SN : SRZ;
#pragma unroll
            for (int q = 0; q < 2; ++q) {
                const float* p1 = Wih1 + row * 64 + q * 32 + lq * 8;
                const float* p2 = Whh1 + row * 64 + q * 32 + lq * 8;
                bf16x8 v1, v2;
#pragma unroll
                for (int i = 0; i < 8; ++i) {
                    v1[i] = f2bf(p1[i] * sc);
                    v2[i] = f2bf(p2[i] * sc);
                }
                w1[g][q] = v1; w2[g][q] = v2;
            }
        }
        const float cb[3] = { SRZ * (bih1[j] + bhh1[j]),
                              SRZ * (bih1[64 + j] + bhh1[64 + j]),
                              SN  * bih1[128 + j] };
        // bhh1_n folded into hg1's C-init (multiplied by r later:
        // n = tanh(r*(Whh1n.h + bhh1n) + Wih1n.h0 + bih1n))
        const float ce2 = SN * bhh1[128 + j];

        f32x2 h01 = {0.f, 0.f}, h23 = {0.f, 0.f};

        for (int t = 0; t <= TSTEPS; ++t) {
            const int pr = t & 1, pw = pr ^ 1;
            bf16x8 a00 = *(const bf16x8*)&h0A[pr][aoff];
            bf16x8 a01 = *(const bf16x8*)&h0A[pr][aoff + 32];
            bf16x8 a10 = *(const bf16x8*)&h1A[pr][aoff];
            bf16x8 a11 = *(const bf16x8*)&h1A[pr][aoff + 32];

            f32x4 xg1[3], hg1[3];
#pragma unroll
            for (int g = 0; g < 3; ++g) {
                const f32x4 ci = {cb[g], cb[g], cb[g], cb[g]};
                const float ev = (g == 2) ? ce2 : 0.0f;
                const f32x4 ei = {ev, ev, ev, ev};
                f32x4 d;
                d = __builtin_amdgcn_mfma_f32_16x16x32_bf16(a00, w1[g][0], ci, 0, 0, 0);
                xg1[g] = __builtin_amdgcn_mfma_f32_16x16x32_bf16(a01, w1[g][1], d, 0, 0, 0);
                f32x4 e;
                e = __builtin_amdgcn_mfma_f32_16x16x32_bf16(a10, w2[g][0], ei, 0, 0, 0);
                hg1[g] = __builtin_amdgcn_mfma_f32_16x16x32_bf16(a11, w2[g][1], e, 0, 0, 0);
            }

            if (t > 0) {
                {   // rows r0+0, r0+1
                    const f32x2 xgr = {xg1[0][0], xg1[0][1]}, hgr = {hg1[0][0], hg1[0][1]};
                    const f32x2 xgz = {xg1[1][0], xg1[1][1]}, hgz = {hg1[1][0], hg1[1][1]};
                    const f32x2 xgn = {xg1[2][0], xg1[2][1]}, hgn = {hg1[2][0], hg1[2][1]};
                    const f32x2 rv = sig2(xgr + hgr);
                    const f32x2 zv = sig2(xgz + hgz);
                    const f32x2 nv = tanh2(fma2(rv, hgn, xgn));
                    const f32x2 hv = fma2(zv, h01 - nv, nv);
                    h01 = hv;
                    h1A[pw][(r0 + 0) * 72 + j] = f2bf(hv[0]);
                    h1A[pw][(r0 + 1) * 72 + j] = f2bf(hv[1]);
                }
                {   // rows r0+2, r0+3
                    const f32x2 xgr = {xg1[0][2], xg1[0][3]}, hgr = {hg1[0][2], hg1[0][3]};
                    const f32x2 xgz = {xg1[1][2], xg1[1][3]}, hgz = {hg1[1][2], hg1[1][3]};
                    const f32x2 xgn = {xg1[2][2], xg1[2][3]}, hgn = {hg1[2][2], hg1[2][3]};
                    const f32x2 rv = sig2(xgr + hgr);
                    const f32x2 zv = sig2(xgz + hgz);
                    const f32x2 nv = tanh2(fma2(rv, hgn, xgn));
                    const f32x2 hv = fma2(zv, h23 - nv, nv);
                    h23 = hv;
                    h1A[pw][(r0 + 2) * 72 + j] = f2bf(hv[0]);
                    h1A[pw][(r0 + 3) * 72 + j] = f2bf(hv[1]);
                }
            }
            __syncthreads();   // barrier 1..513
        }

        __syncthreads();       // barrier 514 (Pf written by L0 waves)
        const float wp1 = Wp[64 + j];
        Pf[r0 + 0][j] += wp1 * h01[0];
        Pf[r0 + 1][j] += wp1 * h01[1];
        Pf[r0 + 2][j] += wp1 * h23[0];
        Pf[r0 + 3][j] += wp1 * h23[1];
        __syncthreads();       // barrier 515
    }

    // ---- final reduce: out[b] = sum_j Pf[row][j] + bp ----
    if (tid < 16) {
        float s = bp[0];
#pragma unroll 8
        for (int k = 0; k < 64; ++k) s += Pf[tid][k];
        out[b0 + tid] = s;
    }
}

extern "C" void kernel_launch(void* const* d_in, const int* in_sizes, int n_in,
                              void* d_out, int out_size, void* d_ws, size_t ws_size,
                              hipStream_t stream) {
    (void)in_sizes; (void)n_in; (void)out_size; (void)d_ws; (void)ws_size;
    gru_fused<<<dim3(BATCH / 16), dim3(512), 0, stream>>>(
        (const float*)d_in[0], (const float*)d_in[1], (const float*)d_in[2],
        (const float*)d_in[3], (const float*)d_in[4], (const float*)d_in[5],
        (const float*)d_in[6], (const float*)d_in[7], (const float*)d_in[8],
        (const float*)d_in[9], (const float*)d_in[10], (float*)d_out);
}

// Round 2
// 348.241 us; speedup vs baseline: 1.1339x; 1.0241x over previous
//
#include <hip/hip_runtime.h>
#include <stdint.h>

#define TSTEPS 512
#define BATCH  4096
// R17 = R16 + (a) v_cvt_pk_bf16_f32 packed h-store conversion, (b) s_setprio(1)
// around MFMA clusters (L0/L1 role diversity per SIMD -> scheduler can prefer
// MFMA wave while sibling runs trans-heavy EW), (c) L1 read-burst split
// (h1A frags+hg MFMAs first, then h0A frags+xg MFMAs).
// R16: 16 rows/block full A-tile, grid 256x512, 1 block/CU, 325 us steady.
// Budget @R16: VALU 868 cyc/SIMD-step (trans 384), MFMA 290, LDS 380/CU,
// stall ~450 (phase-aligned barrier bursts). This round: -VALU insts, -stall.
// Failed variants: R9 swizzle-store, R11 x-in-LDS, R12 4-deep MFMA chains,
// R13 shared-rcp, R14 occupancy push (spill).

typedef __attribute__((ext_vector_type(8))) short bf16x8;
typedef __attribute__((ext_vector_type(4))) float f32x4;
typedef __attribute__((ext_vector_type(2))) float f32x2;

#define SRZ (-1.4426950408889634f)   /* -log2(e): r,z gates */
#define SN  ( 2.8853900817779268f)   /* 2*log2(e): n gate   */

__device__ __forceinline__ short f2bf(float f) {
    uint32_t u = __float_as_uint(f);
    uint32_t r = (u + 0x7fffu + ((u >> 16) & 1u)) >> 16;
    return (short)r;
}
// packed f32x2 -> 2x bf16 (RNE), lo = a, hi = b
__device__ __forceinline__ uint32_t cvt_pk_bf16(float a, float b) {
    uint32_t r;
    asm("v_cvt_pk_bf16_f32 %0, %1, %2" : "=v"(r) : "v"(a), "v"(b));
    return r;
}
__device__ __forceinline__ float fast_rcp(float x) { return __builtin_amdgcn_rcpf(x); }
#if __has_builtin(__builtin_amdgcn_exp2f)
__device__ __forceinline__ float exp2_fast(float x) { return __builtin_amdgcn_exp2f(x); }
#else
__device__ __forceinline__ float exp2_fast(float x) { return __expf(x * 0.6931471805599453f); }
#endif

__device__ __forceinline__ f32x2 fma2(f32x2 a, f32x2 b, f32x2 c) {
    return __builtin_elementwise_fma(a, b, c);
}
__device__ __forceinline__ f32x2 splat2(float s) { return (f32x2){s, s}; }
// sigmoid of pre-scaled arg: rcp(1 + exp2(y)), over 2 rows
__device__ __forceinline__ f32x2 sig2(f32x2 y) {
    f32x2 a = {exp2_fast(y[0]), exp2_fast(y[1])};
    a = a + splat2(1.0f);                     // v_pk_add_f32
    return (f32x2){fast_rcp(a[0]), fast_rcp(a[1])};
}
// tanh of pre-scaled arg: 1 - 2*sig2(y)
__device__ __forceinline__ f32x2 tanh2(f32x2 y) {
    return fma2(splat2(-2.0f), sig2(y), splat2(1.0f));
}

__global__ __launch_bounds__(512, 2) void gru_fused(
    const float* __restrict__ x,     // [T,B,2]
    const float* __restrict__ Wih0,  // [192,2]
    const float* __restrict__ Whh0,  // [192,64]
    const float* __restrict__ bih0,  // [192]
    const float* __restrict__ bhh0,  // [192]
    const float* __restrict__ Wih1,  // [192,64]
    const float* __restrict__ Whh1,  // [192,64]
    const float* __restrict__ bih1,  // [192]
    const float* __restrict__ bhh1,  // [192]
    const float* __restrict__ Wp,    // [128]
    const float* __restrict__ bp,    // [1]
    float* __restrict__ out)         // [B]
{
    const int tid  = threadIdx.x;
    const int wv   = tid >> 6;      // wave 0..7
    const int isL0 = (wv < 4);
    const int w4   = wv & 3;
    const int l    = tid & 63;
    const int lm   = l & 15;        // A row m / n-col within tile
    const int lq   = l >> 4;        // quad
    const int b0   = blockIdx.x * 16;
    const int j    = w4 * 16 + lm;  // hidden index this lane owns

    // All 16 MFMA A rows are live batch rows: row m = batch b0+m.
    // EW lane (lm,lq) owns acc rows lq*4+0..3 at hidden j.
    __shared__ short h0A[2][16 * 72];
    __shared__ short h1A[2][16 * 72];
    __shared__ float Pf[16][64];

    for (int idx = tid; idx < 2 * 16 * 72; idx += 512) {
        ((short*)h0A)[idx] = 0;
        ((short*)h1A)[idx] = 0;
    }
    __syncthreads();

    const int aoff = lm * 72 + lq * 8;  // shorts; +32 for K-half 1
    const int r0   = lq * 4;            // first of this lane's 4 rows

    if (isL0) {
        // ================= layer-0 waves =================
        bf16x8 w0[3][2];   // Whh0, gate-prescaled, single bf16
#pragma unroll
        for (int g = 0; g < 3; ++g) {
            const int row = g * 64 + j;
            const float sc = (g == 2) ? SN : SRZ;
#pragma unroll
            for (int q = 0; q < 2; ++q) {
                const float* p = Whh0 + row * 64 + q * 32 + lq * 8;
                bf16x8 vh;
#pragma unroll
                for (int i = 0; i < 8; ++i) vh[i] = f2bf(p[i] * sc);
                w0[g][q] = vh;
            }
        }
        const f32x2 wr0 = splat2(SRZ * Wih0[j * 2 + 0]), wr1 = splat2(SRZ * Wih0[j * 2 + 1]);
        const f32x2 wz0 = splat2(SRZ * Wih0[(64 + j) * 2 + 0]), wz1 = splat2(SRZ * Wih0[(64 + j) * 2 + 1]);
        const f32x2 wn0 = splat2(SN * Wih0[(128 + j) * 2 + 0]), wn1 = splat2(SN * Wih0[(128 + j) * 2 + 1]);
        const float cb[3] = { SRZ * (bih0[j] + bhh0[j]),
                              SRZ * (bih0[64 + j] + bhh0[64 + j]),
                              SN  * bhh0[128 + j] };
        const f32x2 bn = splat2(SN * bih0[128 + j]);

        f32x2 h01 = {0.f, 0.f}, h23 = {0.f, 0.f};
        const float* xp = x + (size_t)(b0 + r0) * 2;    // 4 rows x 2 floats
        f32x4 xa = *(const f32x4*)xp;
        f32x4 xb = *(const f32x4*)(xp + 4);
        f32x4 xan = xa, xbn = xb;

        for (int t = 0; t <= TSTEPS; ++t) {
            const int pr = t & 1, pw = pr ^ 1;
            bf16x8 a00 = *(const bf16x8*)&h0A[pr][aoff];
            bf16x8 a01 = *(const bf16x8*)&h0A[pr][aoff + 32];

            if (t + 1 < TSTEPS) {
                xp += (size_t)BATCH * 2;
                xan = *(const f32x4*)xp;
                xbn = *(const f32x4*)(xp + 4);
            }

            f32x4 hg0[3];
            __builtin_amdgcn_s_setprio(1);
#pragma unroll
            for (int g = 0; g < 3; ++g) {
                const f32x4 ci = {cb[g], cb[g], cb[g], cb[g]};
                f32x4 c;
                c = __builtin_amdgcn_mfma_f32_16x16x32_bf16(a00, w0[g][0], ci, 0, 0, 0);
                hg0[g] = __builtin_amdgcn_mfma_f32_16x16x32_bf16(a01, w0[g][1], c, 0, 0, 0);
            }
            __builtin_amdgcn_s_setprio(0);

            if (t < TSTEPS) {
                {   // rows r0+0, r0+1 (acc regs 0,1 — adjacent -> free f32x2)
                    const f32x2 x0v = {xa[0], xa[2]}, x1v = {xa[1], xa[3]};
                    const f32x2 hgr = {hg0[0][0], hg0[0][1]};
                    const f32x2 hgz = {hg0[1][0], hg0[1][1]};
                    const f32x2 hgn = {hg0[2][0], hg0[2][1]};
                    const f32x2 rv = sig2(fma2(wr0, x0v, fma2(wr1, x1v, hgr)));
                    const f32x2 zv = sig2(fma2(wz0, x0v, fma2(wz1, x1v, hgz)));
                    const f32x2 nv = tanh2(fma2(rv, hgn, fma2(wn0, x0v, fma2(wn1, x1v, bn))));
                    const f32x2 hv = fma2(zv, h01 - nv, nv);
                    h01 = hv;
                    const uint32_t pk = cvt_pk_bf16(hv[0], hv[1]);
                    h0A[pw][(r0 + 0) * 72 + j] = (short)(pk & 0xffffu);
                    h0A[pw][(r0 + 1) * 72 + j] = (short)(pk >> 16);
                }
                {   // rows r0+2, r0+3 (acc regs 2,3)
                    const f32x2 x0v = {xb[0], xb[2]}, x1v = {xb[1], xb[3]};
                    const f32x2 hgr = {hg0[0][2], hg0[0][3]};
                    const f32x2 hgz = {hg0[1][2], hg0[1][3]};
                    const f32x2 hgn = {hg0[2][2], hg0[2][3]};
                    const f32x2 rv = sig2(fma2(wr0, x0v, fma2(wr1, x1v, hgr)));
                    const f32x2 zv = sig2(fma2(wz0, x0v, fma2(wz1, x1v, hgz)));
                    const f32x2 nv = tanh2(fma2(rv, hgn, fma2(wn0, x0v, fma2(wn1, x1v, bn))));
                    const f32x2 hv = fma2(zv, h23 - nv, nv);
                    h23 = hv;
                    const uint32_t pk = cvt_pk_bf16(hv[0], hv[1]);
                    h0A[pw][(r0 + 2) * 72 + j] = (short)(pk & 0xffffu);
                    h0A[pw][(r0 + 3) * 72 + j] = (short)(pk >> 16);
                }
            }
            xa = xan; xb = xbn;
            __syncthreads();   // barrier 1..513
        }

        const float wp0 = Wp[j];
        Pf[r0 + 0][j] = wp0 * h01[0];
        Pf[r0 + 1][j] = wp0 * h01[1];
        Pf[r0 + 2][j] = wp0 * h23[0];
        Pf[r0 + 3][j] = wp0 * h23[1];
        __syncthreads();       // barrier 514
        __syncthreads();       // barrier 515
    } else {
        // ================= layer-1 waves =================
        bf16x8 w1[3][2], w2[3][2];   // Wih1, Whh1, gate-prescaled, single bf16
#pragma unroll
        for (int g = 0; g < 3; ++g) {
            const int row = g * 64 + j;
            const float sc = (g == 2) ? SN : SRZ;
#pragma unroll
            for (int q = 0; q < 2; ++q) {
                const float* p1 = Wih1 + row * 64 + q * 32 + lq * 8;
                const float* p2 = Whh1 + row * 64 + q * 32 + lq * 8;
                bf16x8 v1, v2;
#pragma unroll
                for (int i = 0; i < 8; ++i) {
                    v1[i] = f2bf(p1[i] * sc);
                    v2[i] = f2bf(p2[i] * sc);
                }
                w1[g][q] = v1; w2[g][q] = v2;
            }
        }
        const float cb[3] = { SRZ * (bih1[j] + bhh1[j]),
                              SRZ * (bih1[64 + j] + bhh1[64 + j]),
                              SN  * bih1[128 + j] };
        // bhh1_n folded into hg1's C-init (multiplied by r later:
        // n = tanh(r*(Whh1n.h + bhh1n) + Wih1n.h0 + bih1n))
        const float ce2 = SN * bhh1[128 + j];

        f32x2 h01 = {0.f, 0.f}, h23 = {0.f, 0.f};

        for (int t = 0; t <= TSTEPS; ++t) {
            const int pr = t & 1, pw = pr ^ 1;
            // --- phase 1: h1 self-recurrence frags + MFMAs first ---
            bf16x8 a10 = *(const bf16x8*)&h1A[pr][aoff];
            bf16x8 a11 = *(const bf16x8*)&h1A[pr][aoff + 32];

            f32x4 xg1[3], hg1[3];
            __builtin_amdgcn_s_setprio(1);
#pragma unroll
            for (int g = 0; g < 3; ++g) {
                const float ev = (g == 2) ? ce2 : 0.0f;
                const f32x4 ei = {ev, ev, ev, ev};
                f32x4 e;
                e = __builtin_amdgcn_mfma_f32_16x16x32_bf16(a10, w2[g][0], ei, 0, 0, 0);
                hg1[g] = __builtin_amdgcn_mfma_f32_16x16x32_bf16(a11, w2[g][1], e, 0, 0, 0);
            }
            __builtin_amdgcn_s_setprio(0);

            // --- phase 2: h0 input frags + MFMAs ---
            bf16x8 a00 = *(const bf16x8*)&h0A[pr][aoff];
            bf16x8 a01 = *(const bf16x8*)&h0A[pr][aoff + 32];

            __builtin_amdgcn_s_setprio(1);
#pragma unroll
            for (int g = 0; g < 3; ++g) {
                const f32x4 ci = {cb[g], cb[g], cb[g], cb[g]};
                f32x4 d;
                d = __builtin_amdgcn_mfma_f32_16x16x32_bf16(a00, w1[g][0], ci, 0, 0, 0);
                xg1[g] = __builtin_amdgcn_mfma_f32_16x16x32_bf16(a01, w1[g][1], d, 0, 0, 0);
            }
            __builtin_amdgcn_s_setprio(0);

            if (t > 0) {
                {   // rows r0+0, r0+1
                    const f32x2 xgr = {xg1[0][0], xg1[0][1]}, hgr = {hg1[0][0], hg1[0][1]};
                    const f32x2 xgz = {xg1[1][0], xg1[1][1]}, hgz = {hg1[1][0], hg1[1][1]};
                    const f32x2 xgn = {xg1[2][0], xg1[2][1]}, hgn = {hg1[2][0], hg1[2][1]};
                    const f32x2 rv = sig2(xgr + hgr);
                    const f32x2 zv = sig2(xgz + hgz);
                    const f32x2 nv = tanh2(fma2(rv, hgn, xgn));
                    const f32x2 hv = fma2(zv, h01 - nv, nv);
                    h01 = hv;
                    const uint32_t pk = cvt_pk_bf16(hv[0], hv[1]);
                    h1A[pw][(r0 + 0) * 72 + j] = (short)(pk & 0xffffu);
                    h1A[pw][(r0 + 1) * 72 + j] = (short)(pk >> 16);
                }
                {   // rows r0+2, r0+3
                    const f32x2 xgr = {xg1[0][2], xg1[0][3]}, hgr = {hg1[0][2], hg1[0][3]};
                    const f32x2 xgz = {xg1[1][2], xg1[1][3]}, hgz = {hg1[1][2], hg1[1][3]};
                    const f32x2 xgn = {xg1[2][2], xg1[2][3]}, hgn = {hg1[2][2], hg1[2][3]};
                    const f32x2 rv = sig2(xgr + hgr);
                    const f32x2 zv = sig2(xgz + hgz);
                    const f32x2 nv = tanh2(fma2(rv, hgn, xgn));
                    const f32x2 hv = fma2(zv, h23 - nv, nv);
                    h23 = hv;
                    const uint32_t pk = cvt_pk_bf16(hv[0], hv[1]);
                    h1A[pw][(r0 + 2) * 72 + j] = (short)(pk & 0xffffu);
                    h1A[pw][(r0 + 3) * 72 + j] = (short)(pk >> 16);
                }
            }
            __syncthreads();   // barrier 1..513
        }

        __syncthreads();       // barrier 514 (Pf written by L0 waves)
        const float wp1 = Wp[64 + j];
        Pf[r0 + 0][j] += wp1 * h01[0];
        Pf[r0 + 1][j] += wp1 * h01[1];
        Pf[r0 + 2][j] += wp1 * h23[0];
        Pf[r0 + 3][j] += wp1 * h23[1];
        __syncthreads();       // barrier 515
    }

    // ---- final reduce: out[b] = sum_j Pf[row][j] + bp ----
    if (tid < 16) {
        float s = bp[0];
#pragma unroll 8
        for (int k = 0; k < 64; ++k) s += Pf[tid][k];
        out[b0 + tid] = s;
    }
}

extern "C" void kernel_launch(void* const* d_in, const int* in_sizes, int n_in,
                              void* d_out, int out_size, void* d_ws, size_t ws_size,
                              hipStream_t stream) {
    (void)in_sizes; (void)n_in; (void)out_size; (void)d_ws; (void)ws_size;
    gru_fused<<<dim3(BATCH / 16), dim3(512), 0, stream>>>(
        (const float*)d_in[0], (const float*)d_in[1], (const float*)d_in[2],
        (const float*)d_in[3], (const float*)d_in[4], (const float*)d_in[5],
        (const float*)d_in[6], (const float*)d_in[7], (const float*)d_in[8],
        (const float*)d_in[9], (const float*)d_in[10], (float*)d_out);
}

// Round 3
// 337.341 us; speedup vs baseline: 1.1706x; 1.0323x over previous
//
#include <hip/hip_runtime.h>
#include <stdint.h>

#define TSTEPS 512
#define BATCH  4096
// R18 = R17 + (a) LDS row stride 72->76 shorts: old stride had 4-way bank
// conflicts on BOTH frag ds_read_b128 (banks 4*lm mod 32, lm/lm+8 collide)
// and h-write b16 (lq 0/2, 1/3 collide); 76 makes writes disjoint-range
// 2-way-free and read bases 6*lm mod 32 = all-distinct -> minimal.
// (b) rational gate fusion: h' = [A(B-1)+h(B+1)]/[(B+1)(A+1)], A=exp2(yz),
// B=exp2(yn) -> one rcp for z+n instead of two (saves 2 of 8 trans/group).
// (c) in-loop barrier = s_waitcnt lgkmcnt(0)+s_barrier (skip vmcnt(0) drain
// of the x prefetch that __syncthreads forces).
// R17: 314.5 us steady, VALU 54.5, Mfma 21.5, conflicts 1.266e7.
// Failed variants: R9 swizzle-store, R11 x-in-LDS, R12 4-deep MFMA chains,
// R13 shared-rcp, R14 occupancy push (spill).

typedef __attribute__((ext_vector_type(8))) short bf16x8;
typedef __attribute__((ext_vector_type(4))) float f32x4;
typedef __attribute__((ext_vector_type(2))) float f32x2;

#define SRZ (-1.4426950408889634f)   /* -log2(e): r,z gates */
#define SN  ( 2.8853900817779268f)   /* 2*log2(e): n gate   */
#define SROW 76                      /* LDS row stride in shorts */

__device__ __forceinline__ short f2bf(float f) {
    uint32_t u = __float_as_uint(f);
    uint32_t r = (u + 0x7fffu + ((u >> 16) & 1u)) >> 16;
    return (short)r;
}
// packed f32x2 -> 2x bf16 (RNE), lo = a, hi = b
__device__ __forceinline__ uint32_t cvt_pk_bf16(float a, float b) {
    uint32_t r;
    asm("v_cvt_pk_bf16_f32 %0, %1, %2" : "=v"(r) : "v"(a), "v"(b));
    return r;
}
__device__ __forceinline__ float fast_rcp(float x) { return __builtin_amdgcn_rcpf(x); }
#if __has_builtin(__builtin_amdgcn_exp2f)
__device__ __forceinline__ float exp2_fast(float x) { return __builtin_amdgcn_exp2f(x); }
#else
__device__ __forceinline__ float exp2_fast(float x) { return __expf(x * 0.6931471805599453f); }
#endif

__device__ __forceinline__ f32x2 fma2(f32x2 a, f32x2 b, f32x2 c) {
    return __builtin_elementwise_fma(a, b, c);
}
__device__ __forceinline__ f32x2 splat2(float s) { return (f32x2){s, s}; }
__device__ __forceinline__ f32x2 exp22(f32x2 y) {
    return (f32x2){exp2_fast(y[0]), exp2_fast(y[1])};
}
__device__ __forceinline__ f32x2 rcp2(f32x2 y) {
    return (f32x2){fast_rcp(y[0]), fast_rcp(y[1])};
}
// sigmoid of pre-scaled arg: rcp(1 + exp2(y)), over 2 rows
__device__ __forceinline__ f32x2 sig2(f32x2 y) {
    return rcp2(exp22(y) + splat2(1.0f));
}
// fused z/n/h' update: yz pre-scaled by SRZ, yn pre-scaled by SN.
// z = 1/(1+A), n = (B-1)/(B+1); h' = (1-z)n + z*h
//    = [A(B-1) + h(B+1)] / [(B+1)(A+1)]
__device__ __forceinline__ f32x2 gru_h(f32x2 yz, f32x2 yn, f32x2 h) {
    const f32x2 A = exp22(yz);
    const f32x2 B = exp22(yn);
    const f32x2 P = A * B;
    const f32x2 u = (P - A) + fma2(h, B, h);            // A*B - A + h*B + h
    const f32x2 d = (P + A) + (B + splat2(1.0f));       // A*B + A + B + 1
    return u * rcp2(d);
}
// in-loop barrier: drain LDS only (keep global x prefetch in flight)
__device__ __forceinline__ void bar_lgkm() {
    asm volatile("s_waitcnt lgkmcnt(0)\n\ts_barrier" ::: "memory");
}

__global__ __launch_bounds__(512, 2) void gru_fused(
    const float* __restrict__ x,     // [T,B,2]
    const float* __restrict__ Wih0,  // [192,2]
    const float* __restrict__ Whh0,  // [192,64]
    const float* __restrict__ bih0,  // [192]
    const float* __restrict__ bhh0,  // [192]
    const float* __restrict__ Wih1,  // [192,64]
    const float* __restrict__ Whh1,  // [192,64]
    const float* __restrict__ bih1,  // [192]
    const float* __restrict__ bhh1,  // [192]
    const float* __restrict__ Wp,    // [128]
    const float* __restrict__ bp,    // [1]
    float* __restrict__ out)         // [B]
{
    const int tid  = threadIdx.x;
    const int wv   = tid >> 6;      // wave 0..7
    const int isL0 = (wv < 4);
    const int w4   = wv & 3;
    const int l    = tid & 63;
    const int lm   = l & 15;        // A row m / n-col within tile
    const int lq   = l >> 4;        // quad
    const int b0   = blockIdx.x * 16;
    const int j    = w4 * 16 + lm;  // hidden index this lane owns

    // All 16 MFMA A rows are live batch rows: row m = batch b0+m.
    // EW lane (lm,lq) owns acc rows lq*4+0..3 at hidden j.
    __shared__ short h0A[2][16 * SROW];
    __shared__ short h1A[2][16 * SROW];
    __shared__ float Pf[16][64];

    for (int idx = tid; idx < 2 * 16 * SROW; idx += 512) {
        ((short*)h0A)[idx] = 0;
        ((short*)h1A)[idx] = 0;
    }
    __syncthreads();

    const int aoff = lm * SROW + lq * 8;  // shorts; +32 for K-half 1
    const int r0   = lq * 4;              // first of this lane's 4 rows

    if (isL0) {
        // ================= layer-0 waves =================
        bf16x8 w0[3][2];   // Whh0, gate-prescaled, single bf16
#pragma unroll
        for (int g = 0; g < 3; ++g) {
            const int row = g * 64 + j;
            const float sc = (g == 2) ? SN : SRZ;
#pragma unroll
            for (int q = 0; q < 2; ++q) {
                const float* p = Whh0 + row * 64 + q * 32 + lq * 8;
                bf16x8 vh;
#pragma unroll
                for (int i = 0; i < 8; ++i) vh[i] = f2bf(p[i] * sc);
                w0[g][q] = vh;
            }
        }
        const f32x2 wr0 = splat2(SRZ * Wih0[j * 2 + 0]), wr1 = splat2(SRZ * Wih0[j * 2 + 1]);
        const f32x2 wz0 = splat2(SRZ * Wih0[(64 + j) * 2 + 0]), wz1 = splat2(SRZ * Wih0[(64 + j) * 2 + 1]);
        const f32x2 wn0 = splat2(SN * Wih0[(128 + j) * 2 + 0]), wn1 = splat2(SN * Wih0[(128 + j) * 2 + 1]);
        const float cb[3] = { SRZ * (bih0[j] + bhh0[j]),
                              SRZ * (bih0[64 + j] + bhh0[64 + j]),
                              SN  * bhh0[128 + j] };
        const f32x2 bn = splat2(SN * bih0[128 + j]);

        f32x2 h01 = {0.f, 0.f}, h23 = {0.f, 0.f};
        const float* xp = x + (size_t)(b0 + r0) * 2;    // 4 rows x 2 floats
        f32x4 xa = *(const f32x4*)xp;
        f32x4 xb = *(const f32x4*)(xp + 4);
        f32x4 xan = xa, xbn = xb;

        for (int t = 0; t <= TSTEPS; ++t) {
            const int pr = t & 1, pw = pr ^ 1;
            bf16x8 a00 = *(const bf16x8*)&h0A[pr][aoff];
            bf16x8 a01 = *(const bf16x8*)&h0A[pr][aoff + 32];

            if (t + 1 < TSTEPS) {
                xp += (size_t)BATCH * 2;
                xan = *(const f32x4*)xp;
                xbn = *(const f32x4*)(xp + 4);
            }

            f32x4 hg0[3];
            __builtin_amdgcn_s_setprio(1);
#pragma unroll
            for (int g = 0; g < 3; ++g) {
                const f32x4 ci = {cb[g], cb[g], cb[g], cb[g]};
                f32x4 c;
                c = __builtin_amdgcn_mfma_f32_16x16x32_bf16(a00, w0[g][0], ci, 0, 0, 0);
                hg0[g] = __builtin_amdgcn_mfma_f32_16x16x32_bf16(a01, w0[g][1], c, 0, 0, 0);
            }
            __builtin_amdgcn_s_setprio(0);

            if (t < TSTEPS) {
                {   // rows r0+0, r0+1 (acc regs 0,1 — adjacent -> free f32x2)
                    const f32x2 x0v = {xa[0], xa[2]}, x1v = {xa[1], xa[3]};
                    const f32x2 hgr = {hg0[0][0], hg0[0][1]};
                    const f32x2 hgz = {hg0[1][0], hg0[1][1]};
                    const f32x2 hgn = {hg0[2][0], hg0[2][1]};
                    const f32x2 rv = sig2(fma2(wr0, x0v, fma2(wr1, x1v, hgr)));
                    const f32x2 yz = fma2(wz0, x0v, fma2(wz1, x1v, hgz));
                    const f32x2 yn = fma2(rv, hgn, fma2(wn0, x0v, fma2(wn1, x1v, bn)));
                    const f32x2 hv = gru_h(yz, yn, h01);
                    h01 = hv;
                    const uint32_t pk = cvt_pk_bf16(hv[0], hv[1]);
                    h0A[pw][(r0 + 0) * SROW + j] = (short)(pk & 0xffffu);
                    h0A[pw][(r0 + 1) * SROW + j] = (short)(pk >> 16);
                }
                {   // rows r0+2, r0+3 (acc regs 2,3)
                    const f32x2 x0v = {xb[0], xb[2]}, x1v = {xb[1], xb[3]};
                    const f32x2 hgr = {hg0[0][2], hg0[0][3]};
                    const f32x2 hgz = {hg0[1][2], hg0[1][3]};
                    const f32x2 hgn = {hg0[2][2], hg0[2][3]};
                    const f32x2 rv = sig2(fma2(wr0, x0v, fma2(wr1, x1v, hgr)));
                    const f32x2 yz = fma2(wz0, x0v, fma2(wz1, x1v, hgz));
                    const f32x2 yn = fma2(rv, hgn, fma2(wn0, x0v, fma2(wn1, x1v, bn)));
                    const f32x2 hv = gru_h(yz, yn, h23);
                    h23 = hv;
                    const uint32_t pk = cvt_pk_bf16(hv[0], hv[1]);
                    h0A[pw][(r0 + 2) * SROW + j] = (short)(pk & 0xffffu);
                    h0A[pw][(r0 + 3) * SROW + j] = (short)(pk >> 16);
                }
            }
            xa = xan; xb = xbn;
            bar_lgkm();        // barrier 1..513
        }

        const float wp0 = Wp[j];
        Pf[r0 + 0][j] = wp0 * h01[0];
        Pf[r0 + 1][j] = wp0 * h01[1];
        Pf[r0 + 2][j] = wp0 * h23[0];
        Pf[r0 + 3][j] = wp0 * h23[1];
        __syncthreads();       // barrier 514
        __syncthreads();       // barrier 515
    } else {
        // ================= layer-1 waves =================
        bf16x8 w1[3][2], w2[3][2];   // Wih1, Whh1, gate-prescaled, single bf16
#pragma unroll
        for (int g = 0; g < 3; ++g) {
            const int row = g * 64 + j;
            const float sc = (g == 2) ? SN : SRZ;
#pragma unroll
            for (int q = 0; q < 2; ++q) {
                const float* p1 = Wih1 + row * 64 + q * 32 + lq * 8;
                const float* p2 = Whh1 + row * 64 + q * 32 + lq * 8;
                bf16x8 v1, v2;
#pragma unroll
                for (int i = 0; i < 8; ++i) {
                    v1[i] = f2bf(p1[i] * sc);
                    v2[i] = f2bf(p2[i] * sc);
                }
                w1[g][q] = v1; w2[g][q] = v2;
            }
        }
        const float cb[3] = { SRZ * (bih1[j] + bhh1[j]),
                              SRZ * (bih1[64 + j] + bhh1[64 + j]),
                              SN  * bih1[128 + j] };
        // bhh1_n folded into hg1's C-init (multiplied by r later:
        // n = tanh(r*(Whh1n.h + bhh1n) + Wih1n.h0 + bih1n))
        const float ce2 = SN * bhh1[128 + j];

        f32x2 h01 = {0.f, 0.f}, h23 = {0.f, 0.f};

        for (int t = 0; t <= TSTEPS; ++t) {
            const int pr = t & 1, pw = pr ^ 1;
            // --- phase 1: h1 self-recurrence frags + MFMAs first ---
            bf16x8 a10 = *(const bf16x8*)&h1A[pr][aoff];
            bf16x8 a11 = *(const bf16x8*)&h1A[pr][aoff + 32];

            f32x4 xg1[3], hg1[3];
            __builtin_amdgcn_s_setprio(1);
#pragma unroll
            for (int g = 0; g < 3; ++g) {
                const float ev = (g == 2) ? ce2 : 0.0f;
                const f32x4 ei = {ev, ev, ev, ev};
                f32x4 e;
                e = __builtin_amdgcn_mfma_f32_16x16x32_bf16(a10, w2[g][0], ei, 0, 0, 0);
                hg1[g] = __builtin_amdgcn_mfma_f32_16x16x32_bf16(a11, w2[g][1], e, 0, 0, 0);
            }
            __builtin_amdgcn_s_setprio(0);

            // --- phase 2: h0 input frags + MFMAs ---
            bf16x8 a00 = *(const bf16x8*)&h0A[pr][aoff];
            bf16x8 a01 = *(const bf16x8*)&h0A[pr][aoff + 32];

            __builtin_amdgcn_s_setprio(1);
#pragma unroll
            for (int g = 0; g < 3; ++g) {
                const f32x4 ci = {cb[g], cb[g], cb[g], cb[g]};
                f32x4 d;
                d = __builtin_amdgcn_mfma_f32_16x16x32_bf16(a00, w1[g][0], ci, 0, 0, 0);
                xg1[g] = __builtin_amdgcn_mfma_f32_16x16x32_bf16(a01, w1[g][1], d, 0, 0, 0);
            }
            __builtin_amdgcn_s_setprio(0);

            if (t > 0) {
                {   // rows r0+0, r0+1
                    const f32x2 xgr = {xg1[0][0], xg1[0][1]}, hgr = {hg1[0][0], hg1[0][1]};
                    const f32x2 xgz = {xg1[1][0], xg1[1][1]}, hgz = {hg1[1][0], hg1[1][1]};
                    const f32x2 xgn = {xg1[2][0], xg1[2][1]}, hgn = {hg1[2][0], hg1[2][1]};
                    const f32x2 rv = sig2(xgr + hgr);
                    const f32x2 yz = xgz + hgz;
                    const f32x2 yn = fma2(rv, hgn, xgn);
                    const f32x2 hv = gru_h(yz, yn, h01);
                    h01 = hv;
                    const uint32_t pk = cvt_pk_bf16(hv[0], hv[1]);
                    h1A[pw][(r0 + 0) * SROW + j] = (short)(pk & 0xffffu);
                    h1A[pw][(r0 + 1) * SROW + j] = (short)(pk >> 16);
                }
                {   // rows r0+2, r0+3
                    const f32x2 xgr = {xg1[0][2], xg1[0][3]}, hgr = {hg1[0][2], hg1[0][3]};
                    const f32x2 xgz = {xg1[1][2], xg1[1][3]}, hgz = {hg1[1][2], hg1[1][3]};
                    const f32x2 xgn = {xg1[2][2], xg1[2][3]}, hgn = {hg1[2][2], hg1[2][3]};
                    const f32x2 rv = sig2(xgr + hgr);
                    const f32x2 yz = xgz + hgz;
                    const f32x2 yn = fma2(rv, hgn, xgn);
                    const f32x2 hv = gru_h(yz, yn, h23);
                    h23 = hv;
                    const uint32_t pk = cvt_pk_bf16(hv[0], hv[1]);
                    h1A[pw][(r0 + 2) * SROW + j] = (short)(pk & 0xffffu);
                    h1A[pw][(r0 + 3) * SROW + j] = (short)(pk >> 16);
                }
            }
            bar_lgkm();        // barrier 1..513
        }

        __syncthreads();       // barrier 514 (Pf written by L0 waves)
        const float wp1 = Wp[64 + j];
        Pf[r0 + 0][j] += wp1 * h01[0];
        Pf[r0 + 1][j] += wp1 * h01[1];
        Pf[r0 + 2][j] += wp1 * h23[0];
        Pf[r0 + 3][j] += wp1 * h23[1];
        __syncthreads();       // barrier 515
    }

    // ---- final reduce: out[b] = sum_j Pf[row][j] + bp ----
    if (tid < 16) {
        float s = bp[0];
#pragma unroll 8
        for (int k = 0; k < 64; ++k) s += Pf[tid][k];
        out[b0 + tid] = s;
    }
}

extern "C" void kernel_launch(void* const* d_in, const int* in_sizes, int n_in,
                              void* d_out, int out_size, void* d_ws, size_t ws_size,
                              hipStream_t stream) {
    (void)in_sizes; (void)n_in; (void)out_size; (void)d_ws; (void)ws_size;
    gru_fused<<<dim3(BATCH / 16), dim3(512), 0, stream>>>(
        (const float*)d_in[0], (const float*)d_in[1], (const float*)d_in[2],
        (const float*)d_in[3], (const float*)d_in[4], (const float*)d_in[5],
        (const float*)d_in[6], (const float*)d_in[7], (const float*)d_in[8],
        (const float*)d_in[9], (const float*)d_in[10], (float*)d_out);
}

// Round 4
// 327.634 us; speedup vs baseline: 1.2052x; 1.0296x over previous
//
#include <hip/hip_runtime.h>
#include <stdint.h>

#define TSTEPS 512
#define BATCH  4096
#define SROW 76                      /* LDS row stride in shorts */
// R19 = R18 + latency-filling: (a) t-loop unrolled x2 -> LDS buffer parity
// compile-time; (b) L0 x-side gate partials px(t+1) precomputed during step t
// in the MFMA shadow (x prefetch depth 2), EW chain starts at hg+px add;
// (c) L1 reads all 4 A-frags upfront (conflict-free since R18) + single MFMA
// prio burst; (d) L0 skips dead t=512 MFMAs.
// Budget @R18 (1421 cyc/step): trans 40x16=640 (at floor: 5 trans/elem),
// regular VALU ~140, MFMA ~90-190, idle ~660 from phase-aligned serial
// segments. This round fills idle with cross-step work.
// R18: 303.7 us steady, VALU 53.3, Mfma 22, conflicts 8.2e4 (solved).
// Failed variants: R9 swizzle-store, R11 x-in-LDS, R12 4-deep MFMA chains,
// R13 shared-rcp, R14 occupancy push (spill). Rejected by model: 32-row/CU
// concentration (doubles per-CU trans -> breakeven).

typedef __attribute__((ext_vector_type(8))) short bf16x8;
typedef __attribute__((ext_vector_type(4))) float f32x4;
typedef __attribute__((ext_vector_type(2))) float f32x2;

#define SRZ (-1.4426950408889634f)   /* -log2(e): r,z gates */
#define SN  ( 2.8853900817779268f)   /* 2*log2(e): n gate   */

struct PX { f32x2 gr0, gz0, gn0, gr1, gz1, gn1; };

__device__ __forceinline__ short f2bf(float f) {
    uint32_t u = __float_as_uint(f);
    uint32_t r = (u + 0x7fffu + ((u >> 16) & 1u)) >> 16;
    return (short)r;
}
// packed f32x2 -> 2x bf16 (RNE), lo = a, hi = b
__device__ __forceinline__ uint32_t cvt_pk_bf16(float a, float b) {
    uint32_t r;
    asm("v_cvt_pk_bf16_f32 %0, %1, %2" : "=v"(r) : "v"(a), "v"(b));
    return r;
}
__device__ __forceinline__ float fast_rcp(float x) { return __builtin_amdgcn_rcpf(x); }
#if __has_builtin(__builtin_amdgcn_exp2f)
__device__ __forceinline__ float exp2_fast(float x) { return __builtin_amdgcn_exp2f(x); }
#else
__device__ __forceinline__ float exp2_fast(float x) { return __expf(x * 0.6931471805599453f); }
#endif

__device__ __forceinline__ f32x2 fma2(f32x2 a, f32x2 b, f32x2 c) {
    return __builtin_elementwise_fma(a, b, c);
}
__device__ __forceinline__ f32x2 splat2(float s) { return (f32x2){s, s}; }
__device__ __forceinline__ f32x2 exp22(f32x2 y) {
    return (f32x2){exp2_fast(y[0]), exp2_fast(y[1])};
}
__device__ __forceinline__ f32x2 rcp2(f32x2 y) {
    return (f32x2){fast_rcp(y[0]), fast_rcp(y[1])};
}
// sigmoid of pre-scaled arg: rcp(1 + exp2(y))
__device__ __forceinline__ f32x2 sig2(f32x2 y) {
    return rcp2(exp22(y) + splat2(1.0f));
}
// fused z/n/h' update: yz pre-scaled by SRZ, yn pre-scaled by SN.
// z = 1/(1+A), n = (B-1)/(B+1); h' = (1-z)n + z*h
//    = [A(B-1) + h(B+1)] / [(B+1)(A+1)]
__device__ __forceinline__ f32x2 gru_h(f32x2 yz, f32x2 yn, f32x2 h) {
    const f32x2 A = exp22(yz);
    const f32x2 B = exp22(yn);
    const f32x2 P = A * B;
    const f32x2 u = (P - A) + fma2(h, B, h);            // A*B - A + h*B + h
    const f32x2 d = (P + A) + (B + splat2(1.0f));       // A*B + A + B + 1
    return u * rcp2(d);
}
// in-loop barrier: drain LDS only (keep global x prefetch in flight)
__device__ __forceinline__ void bar_lgkm() {
    asm volatile("s_waitcnt lgkmcnt(0)\n\ts_barrier" ::: "memory");
}

__global__ __launch_bounds__(512, 2) void gru_fused(
    const float* __restrict__ x,     // [T,B,2]
    const float* __restrict__ Wih0,  // [192,2]
    const float* __restrict__ Whh0,  // [192,64]
    const float* __restrict__ bih0,  // [192]
    const float* __restrict__ bhh0,  // [192]
    const float* __restrict__ Wih1,  // [192,64]
    const float* __restrict__ Whh1,  // [192,64]
    const float* __restrict__ bih1,  // [192]
    const float* __restrict__ bhh1,  // [192]
    const float* __restrict__ Wp,    // [128]
    const float* __restrict__ bp,    // [1]
    float* __restrict__ out)         // [B]
{
    const int tid  = threadIdx.x;
    const int wv   = tid >> 6;      // wave 0..7
    const int isL0 = (wv < 4);
    const int w4   = wv & 3;
    const int l    = tid & 63;
    const int lm   = l & 15;        // A row m / n-col within tile
    const int lq   = l >> 4;        // quad
    const int b0   = blockIdx.x * 16;
    const int j    = w4 * 16 + lm;  // hidden index this lane owns

    __shared__ short h0A[2][16 * SROW];
    __shared__ short h1A[2][16 * SROW];
    __shared__ float Pf[16][64];

    for (int idx = tid; idx < 2 * 16 * SROW; idx += 512) {
        ((short*)h0A)[idx] = 0;
        ((short*)h1A)[idx] = 0;
    }
    __syncthreads();

    const int aoff = lm * SROW + lq * 8;  // shorts; +32 for K-half 1
    const int r0   = lq * 4;              // first of this lane's 4 rows

    if (isL0) {
        // ================= layer-0 waves =================
        bf16x8 w0[3][2];   // Whh0, gate-prescaled, single bf16
#pragma unroll
        for (int g = 0; g < 3; ++g) {
            const int row = g * 64 + j;
            const float sc = (g == 2) ? SN : SRZ;
#pragma unroll
            for (int q = 0; q < 2; ++q) {
                const float* p = Whh0 + row * 64 + q * 32 + lq * 8;
                bf16x8 vh;
#pragma unroll
                for (int i = 0; i < 8; ++i) vh[i] = f2bf(p[i] * sc);
                w0[g][q] = vh;
            }
        }
        const f32x2 wr0 = splat2(SRZ * Wih0[j * 2 + 0]), wr1 = splat2(SRZ * Wih0[j * 2 + 1]);
        const f32x2 wz0 = splat2(SRZ * Wih0[(64 + j) * 2 + 0]), wz1 = splat2(SRZ * Wih0[(64 + j) * 2 + 1]);
        const f32x2 wn0 = splat2(SN * Wih0[(128 + j) * 2 + 0]), wn1 = splat2(SN * Wih0[(128 + j) * 2 + 1]);
        const float cb[3] = { SRZ * (bih0[j] + bhh0[j]),
                              SRZ * (bih0[64 + j] + bhh0[64 + j]),
                              SN  * bhh0[128 + j] };
        const f32x2 bn = splat2(SN * bih0[128 + j]);

        f32x2 h01 = {0.f, 0.f}, h23 = {0.f, 0.f};

        // x pipeline: xE/xO hold x(even t)/x(odd t); loads run 2 steps ahead.
        const float* xb_ = x + (size_t)(b0 + r0) * 2;
        f32x4 xEa = *(const f32x4*)xb_;
        f32x4 xEb = *(const f32x4*)(xb_ + 4);
        f32x4 xOa = *(const f32x4*)(xb_ + (size_t)BATCH * 2);
        f32x4 xOb = *(const f32x4*)(xb_ + (size_t)BATCH * 2 + 4);
        const float* xp = xb_ + 2 * (size_t)BATCH * 2;   // next load = x(2)

        PX pE, pO;
        // px(0) from x(0)
        {
            const f32x2 x0a = {xEa[0], xEa[2]}, x1a = {xEa[1], xEa[3]};
            const f32x2 x0b = {xEb[0], xEb[2]}, x1b = {xEb[1], xEb[3]};
            pE.gr0 = fma2(wr0, x0a, wr1 * x1a);
            pE.gz0 = fma2(wz0, x0a, wz1 * x1a);
            pE.gn0 = fma2(wn0, x0a, fma2(wn1, x1a, bn));
            pE.gr1 = fma2(wr0, x0b, wr1 * x1b);
            pE.gz1 = fma2(wz0, x0b, wz1 * x1b);
            pE.gn1 = fma2(wn0, x0b, fma2(wn1, x1b, bn));
        }

        auto l0_step = [&](int pr, bool doload, PX& u, PX& d,
                           f32x4& xla, f32x4& xlb,
                           const f32x4& xsa, const f32x4& xsb) {
            const int pw = pr ^ 1;
            const bf16x8 a00 = *(const bf16x8*)&h0A[pr][aoff];
            const bf16x8 a01 = *(const bf16x8*)&h0A[pr][aoff + 32];
            if (doload) {
                xla = *(const f32x4*)xp;
                xlb = *(const f32x4*)(xp + 4);
                xp += (size_t)BATCH * 2;
            }
            f32x4 hg0[3];
            __builtin_amdgcn_s_setprio(1);
#pragma unroll
            for (int g = 0; g < 3; ++g) {
                const f32x4 ci = {cb[g], cb[g], cb[g], cb[g]};
                f32x4 c;
                c = __builtin_amdgcn_mfma_f32_16x16x32_bf16(a00, w0[g][0], ci, 0, 0, 0);
                hg0[g] = __builtin_amdgcn_mfma_f32_16x16x32_bf16(a01, w0[g][1], c, 0, 0, 0);
            }
            __builtin_amdgcn_s_setprio(0);
            // px for NEXT step (independent of MFMAs -> fills their shadow)
            {
                const f32x2 x0a = {xsa[0], xsa[2]}, x1a = {xsa[1], xsa[3]};
                const f32x2 x0b = {xsb[0], xsb[2]}, x1b = {xsb[1], xsb[3]};
                d.gr0 = fma2(wr0, x0a, wr1 * x1a);
                d.gz0 = fma2(wz0, x0a, wz1 * x1a);
                d.gn0 = fma2(wn0, x0a, fma2(wn1, x1a, bn));
                d.gr1 = fma2(wr0, x0b, wr1 * x1b);
                d.gz1 = fma2(wz0, x0b, wz1 * x1b);
                d.gn1 = fma2(wn0, x0b, fma2(wn1, x1b, bn));
            }
            {   // rows r0+0, r0+1 (acc regs 0,1)
                const f32x2 hgr = {hg0[0][0], hg0[0][1]};
                const f32x2 hgz = {hg0[1][0], hg0[1][1]};
                const f32x2 hgn = {hg0[2][0], hg0[2][1]};
                const f32x2 rv = sig2(hgr + u.gr0);
                const f32x2 hv = gru_h(hgz + u.gz0, fma2(rv, hgn, u.gn0), h01);
                h01 = hv;
                const uint32_t pk = cvt_pk_bf16(hv[0], hv[1]);
                h0A[pw][(r0 + 0) * SROW + j] = (short)(pk & 0xffffu);
                h0A[pw][(r0 + 1) * SROW + j] = (short)(pk >> 16);
            }
            {   // rows r0+2, r0+3 (acc regs 2,3)
                const f32x2 hgr = {hg0[0][2], hg0[0][3]};
                const f32x2 hgz = {hg0[1][2], hg0[1][3]};
                const f32x2 hgn = {hg0[2][2], hg0[2][3]};
                const f32x2 rv = sig2(hgr + u.gr1);
                const f32x2 hv = gru_h(hgz + u.gz1, fma2(rv, hgn, u.gn1), h23);
                h23 = hv;
                const uint32_t pk = cvt_pk_bf16(hv[0], hv[1]);
                h0A[pw][(r0 + 2) * SROW + j] = (short)(pk & 0xffffu);
                h0A[pw][(r0 + 3) * SROW + j] = (short)(pk >> 16);
            }
        };

        for (int tp = 0; tp < TSTEPS / 2; ++tp) {
            const bool doload = (tp < TSTEPS / 2 - 1);
            l0_step(0, doload, pE, pO, xEa, xEb, xOa, xOb);  // t = 2tp
            bar_lgkm();
            l0_step(1, doload, pO, pE, xOa, xOb, xEa, xEb);  // t = 2tp+1
            bar_lgkm();
        }
        // t=512: L0 has no work (L1 consumes h0(511) this iter)

        const float wp0 = Wp[j];
        Pf[r0 + 0][j] = wp0 * h01[0];
        Pf[r0 + 1][j] = wp0 * h01[1];
        Pf[r0 + 2][j] = wp0 * h23[0];
        Pf[r0 + 3][j] = wp0 * h23[1];
        __syncthreads();
        __syncthreads();
    } else {
        // ================= layer-1 waves =================
        bf16x8 w1[3][2], w2[3][2];   // Wih1, Whh1, gate-prescaled, single bf16
#pragma unroll
        for (int g = 0; g < 3; ++g) {
            const int row = g * 64 + j;
            const float sc = (g == 2) ? SN : SRZ;
#pragma unroll
            for (int q = 0; q < 2; ++q) {
                const float* p1 = Wih1 + row * 64 + q * 32 + lq * 8;
                const float* p2 = Whh1 + row * 64 + q * 32 + lq * 8;
                bf16x8 v1, v2;
#pragma unroll
                for (int i = 0; i < 8; ++i) {
                    v1[i] = f2bf(p1[i] * sc);
                    v2[i] = f2bf(p2[i] * sc);
                }
                w1[g][q] = v1; w2[g][q] = v2;
            }
        }
        const float cb[3] = { SRZ * (bih1[j] + bhh1[j]),
                              SRZ * (bih1[64 + j] + bhh1[64 + j]),
                              SN  * bih1[128 + j] };
        // bhh1_n folded into hg1's C-init (multiplied by r later)
        const float ce2 = SN * bhh1[128 + j];

        f32x2 h01 = {0.f, 0.f}, h23 = {0.f, 0.f};

        auto l1_step = [&](int pr, bool doew, bool dowrite) {
            const int pw = pr ^ 1;
            // all 4 A-frag reads upfront (conflict-free since R18)
            const bf16x8 a10 = *(const bf16x8*)&h1A[pr][aoff];
            const bf16x8 a11 = *(const bf16x8*)&h1A[pr][aoff + 32];
            const bf16x8 a00 = *(const bf16x8*)&h0A[pr][aoff];
            const bf16x8 a01 = *(const bf16x8*)&h0A[pr][aoff + 32];

            f32x4 xg1[3], hg1[3];
            __builtin_amdgcn_s_setprio(1);
#pragma unroll
            for (int g = 0; g < 3; ++g) {
                const float ev = (g == 2) ? ce2 : 0.0f;
                const f32x4 ei = {ev, ev, ev, ev};
                f32x4 e;
                e = __builtin_amdgcn_mfma_f32_16x16x32_bf16(a10, w2[g][0], ei, 0, 0, 0);
                hg1[g] = __builtin_amdgcn_mfma_f32_16x16x32_bf16(a11, w2[g][1], e, 0, 0, 0);
            }
#pragma unroll
            for (int g = 0; g < 3; ++g) {
                const f32x4 ci = {cb[g], cb[g], cb[g], cb[g]};
                f32x4 d;
                d = __builtin_amdgcn_mfma_f32_16x16x32_bf16(a00, w1[g][0], ci, 0, 0, 0);
                xg1[g] = __builtin_amdgcn_mfma_f32_16x16x32_bf16(a01, w1[g][1], d, 0, 0, 0);
            }
            __builtin_amdgcn_s_setprio(0);

            if (doew) {
                {   // rows r0+0, r0+1
                    const f32x2 xgr = {xg1[0][0], xg1[0][1]}, hgr = {hg1[0][0], hg1[0][1]};
                    const f32x2 xgz = {xg1[1][0], xg1[1][1]}, hgz = {hg1[1][0], hg1[1][1]};
                    const f32x2 xgn = {xg1[2][0], xg1[2][1]}, hgn = {hg1[2][0], hg1[2][1]};
                    const f32x2 rv = sig2(xgr + hgr);
                    const f32x2 hv = gru_h(xgz + hgz, fma2(rv, hgn, xgn), h01);
                    h01 = hv;
                    if (dowrite) {
                        const uint32_t pk = cvt_pk_bf16(hv[0], hv[1]);
                        h1A[pw][(r0 + 0) * SROW + j] = (short)(pk & 0xffffu);
                        h1A[pw][(r0 + 1) * SROW + j] = (short)(pk >> 16);
                    }
                }
                {   // rows r0+2, r0+3
                    const f32x2 xgr = {xg1[0][2], xg1[0][3]}, hgr = {hg1[0][2], hg1[0][3]};
                    const f32x2 xgz = {xg1[1][2], xg1[1][3]}, hgz = {hg1[1][2], hg1[1][3]};
                    const f32x2 xgn = {xg1[2][2], xg1[2][3]}, hgn = {hg1[2][2], hg1[2][3]};
                    const f32x2 rv = sig2(xgr + hgr);
                    const f32x2 hv = gru_h(xgz + hgz, fma2(rv, hgn, xgn), h23);
                    h23 = hv;
                    if (dowrite) {
                        const uint32_t pk = cvt_pk_bf16(hv[0], hv[1]);
                        h1A[pw][(r0 + 2) * SROW + j] = (short)(pk & 0xffffu);
                        h1A[pw][(r0 + 3) * SROW + j] = (short)(pk >> 16);
                    }
                }
            }
        };

        for (int tp = 0; tp < TSTEPS / 2; ++tp) {
            l1_step(0, tp > 0, true);   // t = 2tp
            bar_lgkm();
            l1_step(1, true, true);     // t = 2tp+1
            bar_lgkm();
        }
        l1_step(0, true, false);        // t = 512: last L1 update, no store

        __syncthreads();                // Pf written by L0 waves
        const float wp1 = Wp[64 + j];
        Pf[r0 + 0][j] += wp1 * h01[0];
        Pf[r0 + 1][j] += wp1 * h01[1];
        Pf[r0 + 2][j] += wp1 * h23[0];
        Pf[r0 + 3][j] += wp1 * h23[1];
        __syncthreads();
    }

    // ---- final reduce: out[b] = sum_j Pf[row][j] + bp ----
    if (tid < 16) {
        float s = bp[0];
#pragma unroll 8
        for (int k = 0; k < 64; ++k) s += Pf[tid][k];
        out[b0 + tid] = s;
    }
}

extern "C" void kernel_launch(void* const* d_in, const int* in_sizes, int n_in,
                              void* d_out, int out_size, void* d_ws, size_t ws_size,
                              hipStream_t stream) {
    (void)in_sizes; (void)n_in; (void)out_size; (void)d_ws; (void)ws_size;
    gru_fused<<<dim3(BATCH / 16), dim3(512), 0, stream>>>(
        (const float*)d_in[0], (const float*)d_in[1], (const float*)d_in[2],
        (const float*)d_in[3], (const float*)d_in[4], (const float*)d_in[5],
        (const float*)d_in[6], (const float*)d_in[7], (const float*)d_in[8],
        (const float*)d_in[9], (const float*)d_in[10], (float*)d_out);
}